// Round 3
// baseline (415.783 us; speedup 1.0000x reference)
//
#include <hip/hip_runtime.h>
#include <hip/hip_bf16.h>

#define SEQ 2048
#define DM  1024
#define NH  4
#define HD  256

typedef __attribute__((ext_vector_type(4))) float f32x4;
typedef __attribute__((ext_vector_type(8))) short bf16x8;

__device__ __forceinline__ void gload16(const void* g, void* l) {
  __builtin_amdgcn_global_load_lds(
      (__attribute__((address_space(1))) void*)(unsigned long long)(g),
      (__attribute__((address_space(3))) void*)(l), 16, 0, 0);
}

__device__ __forceinline__ bf16x8 ldg8(const __hip_bfloat16* p) {
  return *reinterpret_cast<const bf16x8*>(p);
}

// ---------------- fp32 -> bf16 ----------------
__global__ __launch_bounds__(256) void cvt_f32_bf16(const float* __restrict__ in,
                                                    __hip_bfloat16* __restrict__ out, int n4) {
  int i = blockIdx.x * 256 + threadIdx.x;
  if (i >= n4) return;
  float4 v = reinterpret_cast<const float4*>(in)[i];
  __hip_bfloat162* o2 = reinterpret_cast<__hip_bfloat162*>(out);
  o2[i * 2 + 0] = __float22bfloat162_rn(make_float2(v.x, v.y));
  o2[i * 2 + 1] = __float22bfloat162_rn(make_float2(v.z, v.w));
}

// ---------------- GEMM: C[m,n] = sum_k A[m,k]*B[n,k] (+bias, +resid) ----------------
// 128x128 tile, BK=32, 4 waves, 4x4 16x16x32 frags/wave, global_load_lds staging (m97 structure)
template <int EPI>
__global__ __launch_bounds__(256, 2) void gemm_bt(
    const __hip_bfloat16* __restrict__ A, const __hip_bfloat16* __restrict__ Bw,
    const float* __restrict__ bias, const float* __restrict__ resid,
    __hip_bfloat16* __restrict__ Cb, float* __restrict__ Cf, int M, int N, int K) {
  __shared__ __hip_bfloat16 ldsA[128 * 32];
  __shared__ __hip_bfloat16 ldsB[128 * 32];
  const int t = threadIdx.x;
  const int w = t >> 6, l = t & 63;
  const int lg = l >> 4, li = l & 15;
  const int m0 = blockIdx.y * 128, n0 = blockIdx.x * 128;
  const int wm = (w >> 1) * 64, wn = (w & 1) * 64;
  const int c1 = t + 256;
  const __hip_bfloat16* gA0 = A + (size_t)(m0 + (t >> 2)) * K + (t & 3) * 8;
  const __hip_bfloat16* gA1 = A + (size_t)(m0 + (c1 >> 2)) * K + (c1 & 3) * 8;
  const __hip_bfloat16* gB0 = Bw + (size_t)(n0 + (t >> 2)) * K + (t & 3) * 8;
  const __hip_bfloat16* gB1 = Bw + (size_t)(n0 + (c1 >> 2)) * K + (c1 & 3) * 8;
  __hip_bfloat16* lA0 = ldsA + t * 8;
  __hip_bfloat16* lA1 = ldsA + c1 * 8;
  __hip_bfloat16* lB0 = ldsB + t * 8;
  __hip_bfloat16* lB1 = ldsB + c1 * 8;
  f32x4 acc[4][4] = {};
  for (int k0 = 0; k0 < K; k0 += 32) {
    gload16(gA0 + k0, lA0);
    gload16(gA1 + k0, lA1);
    gload16(gB0 + k0, lB0);
    gload16(gB1 + k0, lB1);
    __syncthreads();
    bf16x8 af[4], bfr[4];
#pragma unroll
    for (int i = 0; i < 4; i++) af[i] = ldg8(&ldsA[(wm + i * 16 + li) * 32 + lg * 8]);
#pragma unroll
    for (int i = 0; i < 4; i++) bfr[i] = ldg8(&ldsB[(wn + i * 16 + li) * 32 + lg * 8]);
#pragma unroll
    for (int mi = 0; mi < 4; mi++)
#pragma unroll
      for (int ni = 0; ni < 4; ni++)
        acc[mi][ni] = __builtin_amdgcn_mfma_f32_16x16x32_bf16(af[mi], bfr[ni], acc[mi][ni], 0, 0, 0);
    __syncthreads();
  }
#pragma unroll
  for (int ni = 0; ni < 4; ni++) {
    const int col = n0 + wn + ni * 16 + li;
    const float bv = bias[col];
#pragma unroll
    for (int mi = 0; mi < 4; mi++) {
      const int rowb = m0 + wm + mi * 16 + lg * 4;
#pragma unroll
      for (int r = 0; r < 4; r++) {
        const size_t idx = (size_t)(rowb + r) * N + col;
        float v = acc[mi][ni][r] + bv;
        if (EPI) {
          Cf[idx] = v + resid[idx];
        } else {
          Cb[idx] = __float2bfloat16(v);
        }
      }
    }
  }
}

// ---------------- V transpose: vt[bh][d][s] <- qkv[.., 2048 + h*256 + d] ----------------
__global__ __launch_bounds__(256) void transpose_v(const short* __restrict__ qkv,
                                                   short* __restrict__ vt) {
  __shared__ short tile[32][36];
  const int t = threadIdx.x;
  const int bh = blockIdx.z, b = bh >> 2, h = bh & 3;
  const int s0 = blockIdx.x * 32, d0 = blockIdx.y * 32;
  const int sr = t >> 3, c4 = (t & 7) * 4;
  const short* src = qkv + (size_t)(b * SEQ + s0 + sr) * 3072 + 2048 + h * HD + d0 + c4;
  short4 vv = *reinterpret_cast<const short4*>(src);
  tile[sr][c4 + 0] = vv.x;
  tile[sr][c4 + 1] = vv.y;
  tile[sr][c4 + 2] = vv.z;
  tile[sr][c4 + 3] = vv.w;
  __syncthreads();
  short* dst = vt + (size_t)(bh * HD + d0 + sr) * SEQ + s0 + c4;
  short4 ov;
  ov.x = tile[c4 + 0][sr];
  ov.y = tile[c4 + 1][sr];
  ov.z = tile[c4 + 2][sr];
  ov.w = tile[c4 + 3][sr];
  *reinterpret_cast<short4*>(dst) = ov;
}

// ---------------- flash attention v5: round-0 structure, V direct from L2 ----------------
// Back to the proven 139us config: 512 blocks (XCD-affine), 4 waves x 16 q-rows, 2 blocks/CU
// = 8 waves/CU (round-2 showed 1 wave/SIMD cannot hide DS latency).
// Changes vs round-0:
//  * V is NOT staged in LDS. With XCD affinity each XCD's 2 bh of K+V (4 MB) are L2-resident
//    (FETCH 25 MB, proven r1/r2); PV reads V fragments directly from vt[bh][d][s]
//    (kv-contiguous => natural 16B/lane load, lg=0..3 read 64B contiguous per d-row).
//    Removes 32 of 66 ds_read_b128/wave-iter + all V staging; ~2.1 GB rides the idle L2 pipe.
//  * K double-buffered (2x32 KB; LDS total 72 KB -> still 2 blocks/CU): issue K(t+1) stage
//    before computing t, one barrier/iter (round-1's pipeline mechanism, mechanically proven).
//  * Row-sums via MFMA(P, ones) into lacc (replaces 16 shfl-adds/iter) [numerics proven r2].
//  * Defer-max THR=8 (skips O-rescale unless max grows >8) [numerics proven r1/r2].
// K/P swizzles byte-identical to round-0 (passing): K stored chunk c at row r holds data
// chunk c^(r&7); P write XOR (q&7), read XOR (li&7).
__global__ __launch_bounds__(256, 2) void flash_attn(const __hip_bfloat16* __restrict__ qkv,
                                                     const __hip_bfloat16* __restrict__ vt,
                                                     __hip_bfloat16* __restrict__ attno) {
  __shared__ __hip_bfloat16 ldsK[2][64 * 256];  // 2 x 32 KB
  __shared__ __hip_bfloat16 ldsP[4][16 * 64];   // 8 KB   (total 72 KB)
  const int tid = threadIdx.x, w = tid >> 6, l = tid & 63;
  const int lg = l >> 4, li = l & 15;
  const int bid = blockIdx.x;
  const int qt = bid >> 4;                          // 0..31 -> 64-row q tiles
  const int bh = (bid & 7) * 2 + ((bid >> 3) & 1);  // XCD-affine: 2 bh per XCD (4 MB = L2)
  const int b = bh >> 2, h = bh & 3;
  const int q0 = qt * 64 + w * 16;
  // Q fragments: A-layout row=li, k=lg*8 contiguous
  const __hip_bfloat16* Qp = qkv + (size_t)(b * SEQ + q0 + li) * 3072 + h * HD + lg * 8;
  bf16x8 aq[8];
#pragma unroll
  for (int kk = 0; kk < 8; kk++) aq[kk] = ldg8(Qp + kk * 32);
  // K staging source base (pre-swizzled global address, rule #21)
  // round i: lds row = i*8 + (tid>>5), stored chunk = tid&31, data chunk = (tid&31)^(row&7)
  const int kcd = (tid & 31) ^ ((tid >> 5) & 7);
  const __hip_bfloat16* Kg = qkv + (size_t)(b * SEQ + (tid >> 5)) * 3072 + 1024 + h * HD + kcd * 8;
  // V fragment base: lane reads vt[bh][d = df*16 + li][kv = kv0 + ks*32 + lg*8 ..+7]
  const __hip_bfloat16* Vb = vt + (size_t)bh * HD * SEQ + (size_t)li * SEQ + lg * 8;
  __hip_bfloat16* Pw = &ldsP[w][0];
  f32x4 oacc[16] = {};
  f32x4 lacc = {};
  float mst[4];
#pragma unroll
  for (int r = 0; r < 4; r++) mst[r] = -1e30f;
  bf16x8 ones;
#pragma unroll
  for (int j = 0; j < 8; j++) ones[j] = (short)0x3F80;  // bf16 1.0
  // prologue: stage K tile 0 into buffer 0
#pragma unroll
  for (int i = 0; i < 8; i++) gload16(Kg + (size_t)(i * 8) * 3072, &ldsK[0][i * 2048 + tid * 8]);
  __syncthreads();
#pragma unroll 2
  for (int t = 0; t < SEQ / 64; ++t) {
    const int cur = t & 1;
    const int kv0 = t * 64;
    // issue next K tile's stage first: latency hides under this tile's compute
    if (t + 1 < SEQ / 64) {
      const int nk = kv0 + 64;
#pragma unroll
      for (int i = 0; i < 8; i++)
        gload16(Kg + (size_t)(nk + i * 8) * 3072, &ldsK[cur ^ 1][i * 2048 + tid * 8]);
    }
    const __hip_bfloat16* Kb = &ldsK[cur][0];
    // ---- QK^T from LDS ----
    f32x4 sacc[4] = {};
#pragma unroll
    for (int kk = 0; kk < 8; kk++) {
#pragma unroll
      for (int nf = 0; nf < 4; nf++) {
        bf16x8 bk = ldg8(&Kb[(nf * 16 + li) * 256 + (((kk * 4 + lg) ^ (li & 7)) << 3)]);
        sacc[nf] = __builtin_amdgcn_mfma_f32_16x16x32_bf16(aq[kk], bk, sacc[nf], 0, 0, 0);
      }
    }
    // ---- online softmax (wave-parallel 16-lane groups, defer-max THR=8) ----
#pragma unroll
    for (int r = 0; r < 4; r++) {
      const float s0 = sacc[0][r] * 0.0625f;  // hd^-0.5
      const float s1 = sacc[1][r] * 0.0625f;
      const float s2 = sacc[2][r] * 0.0625f;
      const float s3 = sacc[3][r] * 0.0625f;
      float rmax = fmaxf(fmaxf(s0, s1), fmaxf(s2, s3));
#pragma unroll
      for (int off = 1; off < 16; off <<= 1) rmax = fmaxf(rmax, __shfl_xor(rmax, off));
      if (rmax > mst[r] + 8.f) {  // group-uniform
        const float alpha = __expf(mst[r] - rmax);
        mst[r] = rmax;
        lacc[r] *= alpha;
#pragma unroll
        for (int df = 0; df < 16; df++) oacc[df][r] *= alpha;
      }
      const float p0 = __expf(s0 - mst[r]);  // bounded by e^8
      const float p1 = __expf(s1 - mst[r]);
      const float p2 = __expf(s2 - mst[r]);
      const float p3 = __expf(s3 - mst[r]);
      const int q = lg * 4 + r;
      const int base = q * 64;
      Pw[base + (((0 + (li >> 3)) ^ (q & 7)) << 3) + (li & 7)] = __float2bfloat16(p0);
      Pw[base + (((2 + (li >> 3)) ^ (q & 7)) << 3) + (li & 7)] = __float2bfloat16(p1);
      Pw[base + (((4 + (li >> 3)) ^ (q & 7)) << 3) + (li & 7)] = __float2bfloat16(p2);
      Pw[base + (((6 + (li >> 3)) ^ (q & 7)) << 3) + (li & 7)] = __float2bfloat16(p3);
    }
    asm volatile("" ::: "memory");
    // ---- PV: P from wave-private LDS, V fragments DIRECT FROM L2 ----
#pragma unroll
    for (int ks = 0; ks < 2; ks++) {
      bf16x8 pa = ldg8(&Pw[li * 64 + (((ks * 4 + lg) ^ (li & 7)) << 3)]);
      lacc = __builtin_amdgcn_mfma_f32_16x16x32_bf16(pa, ones, lacc, 0, 0, 0);
      const __hip_bfloat16* vb = Vb + kv0 + ks * 32;
      bf16x8 bva[8], bvb[8];
#pragma unroll
      for (int j = 0; j < 8; j++) bva[j] = ldg8(vb + (size_t)j * 16 * SEQ);
#pragma unroll
      for (int j = 0; j < 8; j++) bvb[j] = ldg8(vb + (size_t)(8 + j) * 16 * SEQ);
#pragma unroll
      for (int j = 0; j < 8; j++)
        oacc[j] = __builtin_amdgcn_mfma_f32_16x16x32_bf16(pa, bva[j], oacc[j], 0, 0, 0);
#pragma unroll
      for (int j = 0; j < 8; j++)
        oacc[8 + j] = __builtin_amdgcn_mfma_f32_16x16x32_bf16(pa, bvb[j], oacc[8 + j], 0, 0, 0);
    }
    // one barrier per tile: drains in-flight next-K loads AND guards K buffer reuse
    __syncthreads();
  }
  float inv[4];
#pragma unroll
  for (int r = 0; r < 4; r++) inv[r] = 1.f / lacc[r];
  const size_t orow = (size_t)(b * SEQ + q0 + lg * 4);
#pragma unroll
  for (int df = 0; df < 16; df++)
#pragma unroll
    for (int r = 0; r < 4; r++) {
      float v = oacc[df][r] * inv[r];
      attno[(orow + r) * DM + h * HD + df * 16 + li] = __float2bfloat16(v);
    }
}

// ---------------- LayerNorm: 1 wave per 1024-row ----------------
__global__ __launch_bounds__(256) void layernorm_k(const float* __restrict__ y,
                                                   const float* __restrict__ gamma,
                                                   const float* __restrict__ beta,
                                                   float* __restrict__ out) {
  const int w = threadIdx.x >> 6, l = threadIdx.x & 63;
  const size_t row = (size_t)blockIdx.x * 4 + w;
  const float4* yp = reinterpret_cast<const float4*>(y + row * DM);
  float4 v[4];
  float s = 0.f, s2 = 0.f;
#pragma unroll
  for (int i = 0; i < 4; i++) {
    v[i] = yp[i * 64 + l];
    s += v[i].x + v[i].y + v[i].z + v[i].w;
    s2 += v[i].x * v[i].x + v[i].y * v[i].y + v[i].z * v[i].z + v[i].w * v[i].w;
  }
#pragma unroll
  for (int off = 1; off < 64; off <<= 1) {
    s += __shfl_xor(s, off);
    s2 += __shfl_xor(s2, off);
  }
  const float mu = s * (1.f / 1024.f);
  const float rs = rsqrtf(s2 * (1.f / 1024.f) - mu * mu + 1e-5f);
  const float4* gp = reinterpret_cast<const float4*>(gamma);
  const float4* bp = reinterpret_cast<const float4*>(beta);
  float4* op = reinterpret_cast<float4*>(out + row * DM);
#pragma unroll
  for (int i = 0; i < 4; i++) {
    float4 g = gp[i * 64 + l], bb = bp[i * 64 + l];
    float4 o;
    o.x = (v[i].x - mu) * rs * g.x + bb.x;
    o.y = (v[i].y - mu) * rs * g.y + bb.y;
    o.z = (v[i].z - mu) * rs * g.z + bb.z;
    o.w = (v[i].w - mu) * rs * g.w + bb.w;
    op[i * 64 + l] = o;
  }
}

extern "C" void kernel_launch(void* const* d_in, const int* in_sizes, int n_in,
                              void* d_out, int out_size, void* d_ws, size_t ws_size,
                              hipStream_t stream) {
  const float* x     = (const float*)d_in[0];
  const float* qkv_w = (const float*)d_in[1];
  const float* qkv_b = (const float*)d_in[2];
  const float* wo_w  = (const float*)d_in[3];
  const float* wo_b  = (const float*)d_in[4];
  const float* gamma = (const float*)d_in[5];
  const float* beta  = (const float*)d_in[6];
  float* out = (float*)d_out;
  char* ws = (char*)d_ws;
  __hip_bfloat16* xbf   = (__hip_bfloat16*)(ws);
  __hip_bfloat16* qkvwb = (__hip_bfloat16*)(ws + 16777216);
  __hip_bfloat16* wowb  = (__hip_bfloat16*)(ws + 23068672);
  __hip_bfloat16* qkv   = (__hip_bfloat16*)(ws + 25165824);
  float*          yb    = (float*)(ws + 25165824);
  __hip_bfloat16* vt    = (__hip_bfloat16*)(ws + 75497472);
  __hip_bfloat16* attno = xbf;

  cvt_f32_bf16<<<8192, 256, 0, stream>>>(x, xbf, 2097152);
  cvt_f32_bf16<<<3072, 256, 0, stream>>>(qkv_w, qkvwb, 786432);
  cvt_f32_bf16<<<1024, 256, 0, stream>>>(wo_w, wowb, 262144);
  gemm_bt<0><<<dim3(24, 64), 256, 0, stream>>>(xbf, qkvwb, qkv_b, nullptr, qkv, nullptr,
                                               8192, 3072, 1024);
  transpose_v<<<dim3(64, 8, 16), 256, 0, stream>>>((const short*)qkv, (short*)vt);
  flash_attn<<<512, 256, 0, stream>>>(qkv, vt, attno);
  gemm_bt<1><<<dim3(8, 64), 256, 0, stream>>>(attno, wowb, wo_b, x, nullptr, yb,
                                              8192, 1024, 1024);
  layernorm_k<<<2048, 256, 0, stream>>>(yb, gamma, beta, out);
}

// Round 5
// 255.270 us; speedup vs baseline: 1.6288x; 1.6288x over previous
//
#include <hip/hip_runtime.h>
#include <hip/hip_bf16.h>

#define SEQ 2048
#define DM  1024
#define NH  4
#define HD  256

typedef __attribute__((ext_vector_type(4))) float f32x4;
typedef __attribute__((ext_vector_type(16))) float f32x16;
typedef __attribute__((ext_vector_type(8))) short bf16x8;

__device__ __forceinline__ void gload16(const void* g, void* l) {
  __builtin_amdgcn_global_load_lds(
      (__attribute__((address_space(1))) void*)(unsigned long long)(g),
      (__attribute__((address_space(3))) void*)(l), 16, 0, 0);
}

__device__ __forceinline__ bf16x8 ldg8(const __hip_bfloat16* p) {
  return *reinterpret_cast<const bf16x8*>(p);
}

__device__ __forceinline__ unsigned pack2(float a, float b) {
  __hip_bfloat162 t = __float22bfloat162_rn(make_float2(a, b));
  return *reinterpret_cast<unsigned*>(&t);  // short0=a, short1=b
}

__device__ __forceinline__ short bfbits(float x) {
  __hip_bfloat16 h = __float2bfloat16(x);
  return *reinterpret_cast<short*>(&h);
}

// ---------------- fp32 -> bf16 ----------------
__global__ __launch_bounds__(256) void cvt_f32_bf16(const float* __restrict__ in,
                                                    __hip_bfloat16* __restrict__ out, int n4) {
  int i = blockIdx.x * 256 + threadIdx.x;
  if (i >= n4) return;
  float4 v = reinterpret_cast<const float4*>(in)[i];
  __hip_bfloat162* o2 = reinterpret_cast<__hip_bfloat162*>(out);
  o2[i * 2 + 0] = __float22bfloat162_rn(make_float2(v.x, v.y));
  o2[i * 2 + 1] = __float22bfloat162_rn(make_float2(v.z, v.w));
}

// ---------------- GEMM: C[m,n] = sum_k A[m,k]*B[n,k] (+bias, +resid) ----------------
template <int EPI>
__global__ __launch_bounds__(256, 2) void gemm_bt(
    const __hip_bfloat16* __restrict__ A, const __hip_bfloat16* __restrict__ Bw,
    const float* __restrict__ bias, const float* __restrict__ resid,
    __hip_bfloat16* __restrict__ Cb, float* __restrict__ Cf, int M, int N, int K) {
  __shared__ __hip_bfloat16 ldsA[128 * 32];
  __shared__ __hip_bfloat16 ldsB[128 * 32];
  const int t = threadIdx.x;
  const int w = t >> 6, l = t & 63;
  const int lg = l >> 4, li = l & 15;
  const int m0 = blockIdx.y * 128, n0 = blockIdx.x * 128;
  const int wm = (w >> 1) * 64, wn = (w & 1) * 64;
  const int c1 = t + 256;
  const __hip_bfloat16* gA0 = A + (size_t)(m0 + (t >> 2)) * K + (t & 3) * 8;
  const __hip_bfloat16* gA1 = A + (size_t)(m0 + (c1 >> 2)) * K + (c1 & 3) * 8;
  const __hip_bfloat16* gB0 = Bw + (size_t)(n0 + (t >> 2)) * K + (t & 3) * 8;
  const __hip_bfloat16* gB1 = Bw + (size_t)(n0 + (c1 >> 2)) * K + (c1 & 3) * 8;
  __hip_bfloat16* lA0 = ldsA + t * 8;
  __hip_bfloat16* lA1 = ldsA + c1 * 8;
  __hip_bfloat16* lB0 = ldsB + t * 8;
  __hip_bfloat16* lB1 = ldsB + c1 * 8;
  f32x4 acc[4][4] = {};
  for (int k0 = 0; k0 < K; k0 += 32) {
    gload16(gA0 + k0, lA0);
    gload16(gA1 + k0, lA1);
    gload16(gB0 + k0, lB0);
    gload16(gB1 + k0, lB1);
    __syncthreads();
    bf16x8 af[4], bfr[4];
#pragma unroll
    for (int i = 0; i < 4; i++) af[i] = ldg8(&ldsA[(wm + i * 16 + li) * 32 + lg * 8]);
#pragma unroll
    for (int i = 0; i < 4; i++) bfr[i] = ldg8(&ldsB[(wn + i * 16 + li) * 32 + lg * 8]);
#pragma unroll
    for (int mi = 0; mi < 4; mi++)
#pragma unroll
      for (int ni = 0; ni < 4; ni++)
        acc[mi][ni] = __builtin_amdgcn_mfma_f32_16x16x32_bf16(af[mi], bfr[ni], acc[mi][ni], 0, 0, 0);
    __syncthreads();
  }
#pragma unroll
  for (int ni = 0; ni < 4; ni++) {
    const int col = n0 + wn + ni * 16 + li;
    const float bv = bias[col];
#pragma unroll
    for (int mi = 0; mi < 4; mi++) {
      const int rowb = m0 + wm + mi * 16 + lg * 4;
#pragma unroll
      for (int r = 0; r < 4; r++) {
        const size_t idx = (size_t)(rowb + r) * N + col;
        float v = acc[mi][ni][r] + bv;
        if (EPI) {
          Cf[idx] = v + resid[idx];
        } else {
          Cb[idx] = __float2bfloat16(v);
        }
      }
    }
  }
}

// ---------------- V transpose: vt[bh][d][s] <- qkv[.., 2048 + h*256 + d] ----------------
__global__ __launch_bounds__(256) void transpose_v(const short* __restrict__ qkv,
                                                   short* __restrict__ vt) {
  __shared__ short tile[32][36];
  const int t = threadIdx.x;
  const int bh = blockIdx.z, b = bh >> 2, h = bh & 3;
  const int s0 = blockIdx.x * 32, d0 = blockIdx.y * 32;
  const int sr = t >> 3, c4 = (t & 7) * 4;
  const short* src = qkv + (size_t)(b * SEQ + s0 + sr) * 3072 + 2048 + h * HD + d0 + c4;
  short4 vv = *reinterpret_cast<const short4*>(src);
  tile[sr][c4 + 0] = vv.x;
  tile[sr][c4 + 1] = vv.y;
  tile[sr][c4 + 2] = vv.z;
  tile[sr][c4 + 3] = vv.w;
  __syncthreads();
  short* dst = vt + (size_t)(bh * HD + d0 + sr) * SEQ + s0 + c4;
  short4 ov;
  ov.x = tile[c4 + 0][sr];
  ov.y = tile[c4 + 1][sr];
  ov.z = tile[c4 + 2][sr];
  ov.w = tile[c4 + 3][sr];
  *reinterpret_cast<short4*>(dst) = ov;
}

// ---------------- flash attention v7: 32x32 MFMA, in-register softmax, IN-BLOCK kv-split ----
// 512-thread blocks = 8 waves = 2 groups x 4 waves. Group g processes kv half [g*1024,+1024)
// for the SAME 128 q rows (wave pair w / w+4 shares q-subtile (w&3)*32). Final flash-combine
// happens through the (then-dead) K/V LDS => no global partials, no merge kernel, v0 workspace.
// Per wave: 32 q rows; S^T = mfma32x32(A=K, B=Q) so lane owns one q column (q=l&31);
// softmax + P-pack fully in registers (2 shfl_xor(32) exchanges); PV: O^T = mfma32x32(A=V^T, B=P^T).
// Fragment maps (32x32x16): A row=l&31, k=(l>>5)*8+j; B col=l&31, k=(l>>5)*8+j;
// C col=l&31, row=(r&3)+8*(r>>2)+4*(l>>5) [m74/m101].
// P-pack derivation: lane hi owns S^T rows (r&3)+8*(r>>2)+4*hi; per 16-kv slice s16 (regs
// rb=8*s16..+8) lane hi=0 holds kv16 {0-3,8-11}, hi=1 {4-7,12-15}. B-frag needs kv16=hi*8+j:
//   hi=0 keeps a-packs (0-3) + partner's a-packs (4-7); hi=1 takes partner's b-packs (8-11)
//   + keeps own b-packs (12-15).  [v6 selected the opposite halves -> wrong output]
// LDS: 2x(32K K + 32K V) + 2K ml = 130 KB -> 1 block/CU; grid 256 = 16qt x 16bh (XCD-affine
// bh: FETCH 25 MB proven r1-r3) -> 8 waves/CU = 2 waves/SIMD (round-0's TLP).
// Staging swizzles byte-identical to rounds 0-3 (passed): K chunk^=(kv&7), V chunk^=(d&7).
__global__ __launch_bounds__(512, 2) void flash_attn(const __hip_bfloat16* __restrict__ qkv,
                                                     const __hip_bfloat16* __restrict__ vt,
                                                     __hip_bfloat16* __restrict__ attno) {
  __shared__ __hip_bfloat16 ldsK[2][64 * 256];  // [group][kv 64][d 256], chunk ^= kv&7
  __shared__ __hip_bfloat16 ldsV[2][256 * 64];  // [group][d 256][kv 64], chunk ^= d&7
  __shared__ float mlx[8][2][32];               // [wave][m,l][q]
  const int tid = threadIdx.x, w = tid >> 6, l = tid & 63;
  const int l31 = l & 31, hi = l >> 5;
  const int g = w >> 2, gt = tid & 255;
  const int bid = blockIdx.x;
  const int bh = (bid & 7) * 2 + ((bid >> 3) & 1);  // XCD-affine: 2 bh per XCD
  const int qt = bid >> 4;
  const int b = bh >> 2, h = bh & 3;
  const int qsub = qt * 128 + (w & 3) * 32;
  const int kvbase = g * 1024;
  // Q B-frags: bq[kst] = Q[q=l31][kst*16 + hi*8 + j]
  bf16x8 bq[16];
  {
    const __hip_bfloat16* Qp = qkv + (size_t)(b * SEQ + qsub + l31) * 3072 + h * HD + hi * 8;
#pragma unroll
    for (int kst = 0; kst < 16; kst++) bq[kst] = ldg8(Qp + kst * 16);
  }
  // K staging: round i writes rows kv=i*8+(gt>>5); phys chunk gt&31 holds data chunk ^(kv&7)
  const int kcd = (gt & 31) ^ ((gt >> 5) & 7);
  const __hip_bfloat16* Kg =
      qkv + (size_t)(b * SEQ + kvbase + (gt >> 5)) * 3072 + 1024 + h * HD + kcd * 8;
  // V staging: round i writes rows d=i*32+(gt>>3); phys chunk gt&7 holds data chunk ^(d&7)
  const int vcd = (gt & 7) ^ ((gt >> 3) & 7);
  const __hip_bfloat16* Vg =
      vt + (size_t)bh * HD * SEQ + (size_t)(gt >> 3) * SEQ + kvbase + vcd * 8;
  __hip_bfloat16* lK = &ldsK[g][0];
  __hip_bfloat16* lV = &ldsV[g][0];

  f32x16 oacc[8] = {};
  float m_run = -1e30f, lsum = 0.f;

  for (int t = 0; t < 16; ++t) {
    // ---- stage this group's K,V tile (single-buffered; 2-barrier structure) ----
#pragma unroll
    for (int i = 0; i < 8; i++)
      gload16(Kg + (size_t)(t * 64 + i * 8) * 3072, lK + i * 2048 + gt * 8);
#pragma unroll
    for (int i = 0; i < 8; i++)
      gload16(Vg + (size_t)(i * 32) * SEQ + t * 64, lV + i * 2048 + gt * 8);
    __syncthreads();
#pragma unroll
    for (int t32 = 0; t32 < 2; t32++) {
      // ---- S^T[kv32][q]: 16 MFMAs, 2 independent chains ----
      f32x16 sa = {}, sb = {};
      const int krow = t32 * 32 + l31;
      const int ksw = krow & 7;
#pragma unroll
      for (int kst = 0; kst < 8; kst++) {
        bf16x8 aka = ldg8(&lK[krow * 256 + (((4 * kst + hi) ^ ksw) << 3)]);
        bf16x8 akb = ldg8(&lK[krow * 256 + (((4 * kst + 2 + hi) ^ ksw) << 3)]);
        sa = __builtin_amdgcn_mfma_f32_32x32x16_bf16(aka, bq[2 * kst], sa, 0, 0, 0);
        sb = __builtin_amdgcn_mfma_f32_32x32x16_bf16(akb, bq[2 * kst + 1], sb, 0, 0, 0);
      }
#pragma unroll
      for (int r = 0; r < 16; r++) sa[r] = (sa[r] + sb[r]) * 0.0625f;  // hd^-0.5
      // ---- in-register online softmax (lane owns q=l31; partner l^32 has other 16 rows) ----
      float rmax = sa[0];
#pragma unroll
      for (int r = 1; r < 16; r++) rmax = fmaxf(rmax, sa[r]);
      rmax = fmaxf(rmax, __shfl_xor(rmax, 32));
      if (rmax > m_run + 8.f) {  // defer-max THR=8
        const float alpha = __expf(m_run - rmax);
        m_run = rmax;
        lsum *= alpha;
#pragma unroll
        for (int dt = 0; dt < 8; dt++)
#pragma unroll
          for (int r = 0; r < 16; r++) oacc[dt][r] *= alpha;
      }
      float psum = 0.f;
#pragma unroll
      for (int r = 0; r < 16; r++) {
        sa[r] = __expf(sa[r] - m_run);  // bounded by e^8
        psum += sa[r];
      }
      lsum += psum + __shfl_xor(psum, 32);
      // ---- pack P^T into B-frags + PV ----
#pragma unroll
      for (int s16 = 0; s16 < 2; s16++) {
        const int rb = s16 * 8;
        // own packs: a* = kv16 (4hi+0,4hi+1),(4hi+2,4hi+3); b* = kv16 (8+4hi..11+4hi)
        unsigned a0 = pack2(sa[rb + 0], sa[rb + 1]);
        unsigned a1 = pack2(sa[rb + 2], sa[rb + 3]);
        unsigned b0 = pack2(sa[rb + 4], sa[rb + 5]);
        unsigned b1 = pack2(sa[rb + 6], sa[rb + 7]);
        // exchange: hi=0 sends b*, receives partner a* (kv16 4-7);
        //           hi=1 sends a*, receives partner b* (kv16 8-11)
        unsigned s0 = (unsigned)__shfl_xor((int)(hi ? a0 : b0), 32);
        unsigned s1 = (unsigned)__shfl_xor((int)(hi ? a1 : b1), 32);
        union { unsigned u[4]; bf16x8 v; } pw;
        pw.u[0] = hi ? s0 : a0;  // k = hi*8 + {0,1}
        pw.u[1] = hi ? s1 : a1;  // k = hi*8 + {2,3}
        pw.u[2] = hi ? b0 : s0;  // k = hi*8 + {4,5}
        pw.u[3] = hi ? b1 : s1;  // k = hi*8 + {6,7}
        // PV: O^T[d][q] += V^T[d][kv] * P^T[kv][q]; A-frag k=hi*8+j -> data chunk t32*4+s16*2+hi
        const int vch = t32 * 4 + s16 * 2 + hi;
#pragma unroll
        for (int dt = 0; dt < 8; dt++) {
          const int drow = dt * 32 + l31;
          bf16x8 av = ldg8(&lV[drow * 64 + ((vch ^ (drow & 7)) << 3)]);
          oacc[dt] = __builtin_amdgcn_mfma_f32_32x32x16_bf16(av, pw.v, oacc[dt], 0, 0, 0);
        }
      }
    }
    __syncthreads();  // all group waves done reading before next stage overwrites
  }
  // ---- cross-group flash-combine (through dead K/V LDS; no global partials) ----
  if (l < 32) {
    mlx[w][0][l] = m_run;
    mlx[w][1][l] = lsum;
  }
  __syncthreads();
  {
    const float m_o = mlx[w ^ 4][0][l31];
    const float l_o = mlx[w ^ 4][1][l31];
    const float mm = fmaxf(m_run, m_o);
    const float e_s = __expf(m_run - mm), e_o = __expf(m_o - mm);
    const float wgt = e_s / (e_s * lsum + e_o * l_o);
#pragma unroll
    for (int dt = 0; dt < 8; dt++)
#pragma unroll
      for (int r = 0; r < 16; r++) oacc[dt][r] *= wgt;
  }
  const int pair = w & 3;
  float* xch = pair < 2 ? reinterpret_cast<float*>(&ldsK[0][0]) + pair * 8192
                        : reinterpret_cast<float*>(&ldsV[0][0]) + (pair - 2) * 8192;
  // exchange layout: float[32 q][256 d], 16B d-chunk swizzled ^ (q&7)
  if (g == 0) {
#pragma unroll
    for (int dt = 0; dt < 8; dt++)
#pragma unroll
      for (int rq = 0; rq < 4; rq++) {
        const int dch = dt * 8 + 2 * rq + hi;
        f32x4 v;
#pragma unroll
        for (int i = 0; i < 4; i++) v[i] = oacc[dt][4 * rq + i];
        *reinterpret_cast<f32x4*>(&xch[l31 * 256 + ((dch ^ (l31 & 7)) << 2)]) = v;
      }
  }
  __syncthreads();
  if (g == 1) {
    const size_t rowb = (size_t)(b * SEQ + qsub + l31) * DM + h * HD;
#pragma unroll
    for (int dt = 0; dt < 8; dt++)
#pragma unroll
      for (int rq = 0; rq < 4; rq++) {
        const int dch = dt * 8 + 2 * rq + hi;
        f32x4 p = *reinterpret_cast<const f32x4*>(&xch[l31 * 256 + ((dch ^ (l31 & 7)) << 2)]);
        short4 sv;
        sv.x = bfbits(p[0] + oacc[dt][4 * rq + 0]);
        sv.y = bfbits(p[1] + oacc[dt][4 * rq + 1]);
        sv.z = bfbits(p[2] + oacc[dt][4 * rq + 2]);
        sv.w = bfbits(p[3] + oacc[dt][4 * rq + 3]);
        *reinterpret_cast<short4*>(
            reinterpret_cast<short*>(attno + rowb + dt * 32 + 8 * rq + 4 * hi)) = sv;
      }
  }
}

// ---------------- LayerNorm: 1 wave per 1024-row ----------------
__global__ __launch_bounds__(256) void layernorm_k(const float* __restrict__ y,
                                                   const float* __restrict__ gamma,
                                                   const float* __restrict__ beta,
                                                   float* __restrict__ out) {
  const int w = threadIdx.x >> 6, l = threadIdx.x & 63;
  const size_t row = (size_t)blockIdx.x * 4 + w;
  const float4* yp = reinterpret_cast<const float4*>(y + row * DM);
  float4 v[4];
  float s = 0.f, s2 = 0.f;
#pragma unroll
  for (int i = 0; i < 4; i++) {
    v[i] = yp[i * 64 + l];
    s += v[i].x + v[i].y + v[i].z + v[i].w;
    s2 += v[i].x * v[i].x + v[i].y * v[i].y + v[i].z * v[i].z + v[i].w * v[i].w;
  }
#pragma unroll
  for (int off = 1; off < 64; off <<= 1) {
    s += __shfl_xor(s, off);
    s2 += __shfl_xor(s2, off);
  }
  const float mu = s * (1.f / 1024.f);
  const float rs = rsqrtf(s2 * (1.f / 1024.f) - mu * mu + 1e-5f);
  const float4* gp = reinterpret_cast<const float4*>(gamma);
  const float4* bp = reinterpret_cast<const float4*>(beta);
  float4* op = reinterpret_cast<float4*>(out + row * DM);
#pragma unroll
  for (int i = 0; i < 4; i++) {
    float4 g = gp[i * 64 + l], bb = bp[i * 64 + l];
    float4 o;
    o.x = (v[i].x - mu) * rs * g.x + bb.x;
    o.y = (v[i].y - mu) * rs * g.y + bb.y;
    o.z = (v[i].z - mu) * rs * g.z + bb.z;
    o.w = (v[i].w - mu) * rs * g.w + bb.w;
    op[i * 64 + l] = o;
  }
}

extern "C" void kernel_launch(void* const* d_in, const int* in_sizes, int n_in,
                              void* d_out, int out_size, void* d_ws, size_t ws_size,
                              hipStream_t stream) {
  const float* x     = (const float*)d_in[0];
  const float* qkv_w = (const float*)d_in[1];
  const float* qkv_b = (const float*)d_in[2];
  const float* wo_w  = (const float*)d_in[3];
  const float* wo_b  = (const float*)d_in[4];
  const float* gamma = (const float*)d_in[5];
  const float* beta  = (const float*)d_in[6];
  float* out = (float*)d_out;
  char* ws = (char*)d_ws;
  // v0 workspace layout (passed 4x): strictly sequential lifetimes, no overlap while live.
  __hip_bfloat16* xbf   = (__hip_bfloat16*)(ws);             // dead after gemm<0>
  __hip_bfloat16* qkvwb = (__hip_bfloat16*)(ws + 16777216);  // dead after gemm<0>
  __hip_bfloat16* wowb  = (__hip_bfloat16*)(ws + 23068672);  // live until gemm<1>
  __hip_bfloat16* qkv   = (__hip_bfloat16*)(ws + 25165824);  // dead after flash
  float*          yb    = (float*)(ws + 25165824);           // gemm<1> out (aliases dead qkv)
  __hip_bfloat16* vt    = (__hip_bfloat16*)(ws + 75497472);  // dead after flash
  __hip_bfloat16* attno = xbf;                               // flash out (aliases dead xbf)

  cvt_f32_bf16<<<8192, 256, 0, stream>>>(x, xbf, 2097152);
  cvt_f32_bf16<<<3072, 256, 0, stream>>>(qkv_w, qkvwb, 786432);
  cvt_f32_bf16<<<1024, 256, 0, stream>>>(wo_w, wowb, 262144);
  gemm_bt<0><<<dim3(24, 64), 256, 0, stream>>>(xbf, qkvwb, qkv_b, nullptr, qkv, nullptr,
                                               8192, 3072, 1024);
  transpose_v<<<dim3(64, 8, 16), 256, 0, stream>>>((const short*)qkv, (short*)vt);
  flash_attn<<<256, 512, 0, stream>>>(qkv, vt, attno);
  gemm_bt<1><<<dim3(8, 64), 256, 0, stream>>>(attno, wowb, wo_b, x, nullptr, yb,
                                              8192, 1024, 1024);
  layernorm_k<<<2048, 256, 0, stream>>>(yb, gamma, beta, out);
}